// Round 2
// baseline (317.381 us; speedup 1.0000x reference)
//
#include <hip/hip_runtime.h>
#include <hip/hip_bf16.h>

#define S_LEN 2048
#define DH 128
#define NBH 32   // B*H = 2*16

typedef __attribute__((ext_vector_type(4))) float f32x4;
typedef __attribute__((ext_vector_type(8))) _Float16 h16x8;
typedef __attribute__((ext_vector_type(4))) _Float16 h16x4;

static __device__ __forceinline__ short f2hs(float f) {
  _Float16 h = (_Float16)f;
  union { _Float16 h; short s; } u;
  u.h = h;
  return u.s;
}

static __device__ __forceinline__ unsigned pk2(float lo, float hi) {
  return (unsigned)(unsigned short)f2hs(lo) | ((unsigned)(unsigned short)f2hs(hi) << 16);
}

// One block: 64 query rows of one (b,h). 4 waves, 16 rows/wave.
// Key tiles of 32. Scores computed as S^T = K * Q^T so query index = lane&15.
__global__ __launch_bounds__(256, 2)
void attn_fwd(const float* __restrict__ Q, const float* __restrict__ K,
              const float* __restrict__ V, const float* __restrict__ scale,
              float* __restrict__ O) {
  // K tile: 32 rows x 128 d, padded to 136 halves/row (272B: b128-aligned, 2-way banks)
  __shared__ short Ks[32 * 136];
  // V tile transposed: Vt[d][k], 128 rows x 32 k padded to 40 halves (80B rows, b64-aligned)
  __shared__ short Vt[128 * 40];

  const int tid  = threadIdx.x;
  const int w    = tid >> 6;
  const int lane = tid & 63;
  const int quad = lane >> 4;
  const int l16  = lane & 15;

  const int bh = blockIdx.y;
  const int q0 = blockIdx.x * 64;
  const size_t base = (size_t)bh * S_LEN * DH;

  const float sc = scale[0];

  // Q fragments (B-operand layout): qf[f][j] = Q[qrow][f*32 + quad*8 + j]
  const int qrow = q0 + w * 16 + l16;
  h16x8 qf[4];
  {
    const float* qp = Q + base + (size_t)qrow * DH + quad * 8;
#pragma unroll
    for (int f = 0; f < 4; ++f) {
      f32x4 a = *(const f32x4*)(qp + f * 32);
      f32x4 b = *(const f32x4*)(qp + f * 32 + 4);
      h16x8 v;
      v[0] = (_Float16)a[0]; v[1] = (_Float16)a[1]; v[2] = (_Float16)a[2]; v[3] = (_Float16)a[3];
      v[4] = (_Float16)b[0]; v[5] = (_Float16)b[1]; v[6] = (_Float16)b[2]; v[7] = (_Float16)b[3];
      qf[f] = v;
    }
  }

  f32x4 Oacc[8];
#pragma unroll
  for (int i = 0; i < 8; ++i) Oacc[i] = (f32x4){0.f, 0.f, 0.f, 0.f};
  float m_run = -1e30f, l_run = 0.f;

  const int wq_max = q0 + w * 16 + 15;   // last query row this wave owns
  const int nkt = q0 / 32 + 2;           // key tiles needed by the whole block

  // staging index precompute
  const int krow = tid >> 3, kcol = (tid & 7) * 16;       // K: 8 threads/row
  const int vk = (tid >> 5) * 4, vd = (tid & 31) * 4;     // V: 4x4 register transpose

  for (int kt = 0; kt < nkt; ++kt) {
    const int k0 = kt * 32;

    // ---- stage K tile (row-major f16) ----
    {
      const float* kp = K + base + (size_t)(k0 + krow) * DH + kcol;
      f32x4 a0 = *(const f32x4*)(kp);
      f32x4 a1 = *(const f32x4*)(kp + 4);
      f32x4 a2 = *(const f32x4*)(kp + 8);
      f32x4 a3 = *(const f32x4*)(kp + 12);
      h16x8 w0, w1;
      w0[0] = (_Float16)a0[0]; w0[1] = (_Float16)a0[1]; w0[2] = (_Float16)a0[2]; w0[3] = (_Float16)a0[3];
      w0[4] = (_Float16)a1[0]; w0[5] = (_Float16)a1[1]; w0[6] = (_Float16)a1[2]; w0[7] = (_Float16)a1[3];
      w1[0] = (_Float16)a2[0]; w1[1] = (_Float16)a2[1]; w1[2] = (_Float16)a2[2]; w1[3] = (_Float16)a2[3];
      w1[4] = (_Float16)a3[0]; w1[5] = (_Float16)a3[1]; w1[6] = (_Float16)a3[2]; w1[7] = (_Float16)a3[3];
      *(h16x8*)&Ks[krow * 136 + kcol]     = w0;
      *(h16x8*)&Ks[krow * 136 + kcol + 8] = w1;
    }
    // ---- stage V tile transposed via 4x4 register transpose ----
    {
      const float* vp = V + base + (size_t)(k0 + vk) * DH + vd;
      f32x4 r0 = *(const f32x4*)(vp);
      f32x4 r1 = *(const f32x4*)(vp + DH);
      f32x4 r2 = *(const f32x4*)(vp + 2 * DH);
      f32x4 r3 = *(const f32x4*)(vp + 3 * DH);
#pragma unroll
      for (int i = 0; i < 4; ++i) {
        h16x4 t4;
        t4[0] = (_Float16)r0[i]; t4[1] = (_Float16)r1[i];
        t4[2] = (_Float16)r2[i]; t4[3] = (_Float16)r3[i];
        *(h16x4*)&Vt[(vd + i) * 40 + vk] = t4;
      }
    }
    __syncthreads();

    if (k0 <= wq_max) {   // wave-uniform: skip fully-masked tiles
      // ---- S^T = K * Q^T : row = key (quad*4+reg), col = query (l16) ----
      f32x4 st[2] = {{0.f,0.f,0.f,0.f},{0.f,0.f,0.f,0.f}};
#pragma unroll
      for (int t16 = 0; t16 < 2; ++t16) {
#pragma unroll
        for (int f = 0; f < 4; ++f) {
          h16x8 kf = *(const h16x8*)&Ks[(t16 * 16 + l16) * 136 + f * 32 + quad * 8];
          st[t16] = __builtin_amdgcn_mfma_f32_16x16x32_f16(kf, qf[f], st[t16], 0, 0, 0);
        }
      }
      // ---- scale + causal mask ----
      float s8[8];
#pragma unroll
      for (int t16 = 0; t16 < 2; ++t16)
#pragma unroll
        for (int r = 0; r < 4; ++r) {
          const int key = k0 + t16 * 16 + quad * 4 + r;
          const float v = st[t16][r] * sc;
          s8[t16 * 4 + r] = (key > qrow) ? -1e30f : v;
        }
      // ---- online softmax (per query = per l16 column) ----
      float mt = s8[0];
#pragma unroll
      for (int i = 1; i < 8; ++i) mt = fmaxf(mt, s8[i]);
      mt = fmaxf(mt, __shfl_xor(mt, 16));
      mt = fmaxf(mt, __shfl_xor(mt, 32));
      const float m_new = fmaxf(m_run, mt);
      float p8[8], rs = 0.f;
#pragma unroll
      for (int i = 0; i < 8; ++i) { p8[i] = __expf(s8[i] - m_new); rs += p8[i]; }
      rs += __shfl_xor(rs, 16);
      rs += __shfl_xor(rs, 32);
      const float alpha = __expf(m_run - m_new);
      l_run = l_run * alpha + rs;
      m_run = m_new;
      // ---- rescale O (O rows are quad*4+r -> fetch that query's alpha) ----
      float aO[4];
#pragma unroll
      for (int r = 0; r < 4; ++r) aO[r] = __shfl(alpha, quad * 4 + r);
#pragma unroll
      for (int dt = 0; dt < 8; ++dt)
#pragma unroll
        for (int r = 0; r < 4; ++r) Oacc[dt][r] *= aO[r];
      // ---- pack P (f16 pairs) and transform C-layout -> A-layout via shuffles ----
      unsigned pd[4];
#pragma unroll
      for (int t16 = 0; t16 < 2; ++t16)
#pragma unroll
        for (int h = 0; h < 2; ++h)
          pd[t16 * 2 + h] = pk2(p8[t16 * 4 + 2 * h], p8[t16 * 4 + 2 * h + 1]);
      union { h16x8 v; int u[4]; } pa;
#pragma unroll
      for (int hp = 0; hp < 4; ++hp) {
        const int quad_s = 2 * (quad & 1) + (hp >> 1);
        const int src = quad_s * 16 + l16;
        const int va = __shfl((int)pd[hp & 1], src);
        const int vb = __shfl((int)pd[2 + (hp & 1)], src);
        pa.u[hp] = (quad >= 2) ? vb : va;
      }
      // ---- O += P * V ----
#pragma unroll
      for (int dt = 0; dt < 8; ++dt) {
        union { h16x8 v; h16x4 h[2]; } vf;
        vf.h[0] = *(const h16x4*)&Vt[(dt * 16 + l16) * 40 + quad * 8];
        vf.h[1] = *(const h16x4*)&Vt[(dt * 16 + l16) * 40 + quad * 8 + 4];
        Oacc[dt] = __builtin_amdgcn_mfma_f32_16x16x32_f16(pa.v, vf.v, Oacc[dt], 0, 0, 0);
      }
    }
    __syncthreads();
  }

  // ---- epilogue: normalize and store (O row = quad*4+r, col = dt*16+l16) ----
  float lO[4];
#pragma unroll
  for (int r = 0; r < 4; ++r) lO[r] = 1.0f / __shfl(l_run, quad * 4 + r);
#pragma unroll
  for (int dt = 0; dt < 8; ++dt)
#pragma unroll
    for (int r = 0; r < 4; ++r) {
      const size_t row = q0 + w * 16 + quad * 4 + r;
      O[base + row * DH + dt * 16 + l16] = Oacc[dt][r] * lO[r];
    }
}

extern "C" void kernel_launch(void* const* d_in, const int* in_sizes, int n_in,
                              void* d_out, int out_size, void* d_ws, size_t ws_size,
                              hipStream_t stream) {
  const float* Q  = (const float*)d_in[0];
  const float* K  = (const float*)d_in[1];
  const float* V  = (const float*)d_in[2];
  const float* sc = (const float*)d_in[3];
  float* O = (float*)d_out;
  dim3 grid(S_LEN / 64, NBH);
  attn_fwd<<<grid, dim3(256), 0, stream>>>(Q, K, V, sc, O);
}

// Round 5
// 264.644 us; speedup vs baseline: 1.1993x; 1.1993x over previous
//
#include <hip/hip_runtime.h>
#include <hip/hip_bf16.h>

#define S_LEN 2048
#define DH    128
#define NBH   32
#define NQT   32          // 64-row q-tiles per (b,h)
#define KPAD  136         // Ks row pitch in halves (272B)
#define VPAD  72          // Vt row pitch in halves (144B)

typedef __attribute__((ext_vector_type(4))) float    f32x4;
typedef __attribute__((ext_vector_type(8))) _Float16 h16x8;
typedef __attribute__((ext_vector_type(4))) _Float16 h16x4;
typedef __attribute__((ext_vector_type(2))) __fp16   fp16x2;

#if __has_builtin(__builtin_amdgcn_exp2f)
#define EXP2(x) __builtin_amdgcn_exp2f(x)
#else
#define EXP2(x) exp2f(x)
#endif

static __device__ __forceinline__ unsigned pk2(float lo, float hi) {
  union { fp16x2 h; unsigned u; } u;
  u.h = __builtin_amdgcn_cvt_pkrtz(lo, hi);
  return u.u;
}

// Block = 64 query rows; 4 waves x 16 rows. Causal pairing: block bx does
// q-tiles {bx, 31-bx} -> constant 33 key-tiles of 64 per block (no tail).
__global__ __launch_bounds__(256, 2)
void attn_fwd(const float* __restrict__ Q, const float* __restrict__ K,
              const float* __restrict__ V, const float* __restrict__ scale,
              float* __restrict__ O) {
  __shared__ short Ks[64 * KPAD];   // K tile row-major f16
  __shared__ short Vt[128 * VPAD];  // V tile transposed, 8B-block XOR swizzled

  const int tid  = threadIdx.x;
  const int w    = tid >> 6;
  const int lane = tid & 63;
  const int quad = lane >> 4;
  const int l16  = lane & 15;

  const int bh = blockIdx.y;
  const size_t base = (size_t)bh * (S_LEN * DH);
  const float sc = scale[0] * 1.44269504088896340736f;  // fold log2(e): exp -> exp2

  // staging indices
  const int krow = tid >> 2, kcolf = (tid & 3) * 32;    // K: 4 threads/row, 32 floats each
  const int vd = (tid & 31) * 4, vkb = (tid >> 5) * 4;  // V: 4k x 4d register transpose

  // Vt read addressing (halves), k-loop invariant.
  // Swizzle (in 4-half blocks): blk_phys = blk_log ^ mm, mm = (row^(row>>4))&14.
  // Row base and within-row offset kept SEPARATE: VPAD*row is not 64-aligned,
  // so the h-half flip (h<<5) must apply to the within-row offset only.
  int vrow[8], voff[8];
#pragma unroll
  for (int dt = 0; dt < 8; ++dt) {
    const int row = dt * 16 + l16;
    const int mm = (row ^ (row >> 4)) & 14;
    vrow[dt] = row * VPAD;
    voff[dt] = ((quad * 2) ^ mm) << 2;
  }

  f32x4 ka[8], va[8];  // prefetch registers

#pragma unroll 1
  for (int phase = 0; phase < 2; ++phase) {
    const int jq = phase ? (NQT - 1 - (int)blockIdx.x) : (int)blockIdx.x;
    const int q0 = jq * 64;
    const int nkt = jq + 1;
    const int qrow = q0 + w * 16 + l16;

    // Q fragment (B-operand), pre-scaled by scale*log2e
    h16x8 qf[4];
    {
      const float* qp = Q + base + (size_t)qrow * DH + quad * 8;
#pragma unroll
      for (int f = 0; f < 4; ++f) {
        f32x4 a = *(const f32x4*)(qp + f * 32);
        f32x4 b = *(const f32x4*)(qp + f * 32 + 4);
        union { h16x8 v; unsigned u[4]; } t;
        t.u[0] = pk2(a[0] * sc, a[1] * sc);
        t.u[1] = pk2(a[2] * sc, a[3] * sc);
        t.u[2] = pk2(b[0] * sc, b[1] * sc);
        t.u[3] = pk2(b[2] * sc, b[3] * sc);
        qf[f] = t.v;
      }
    }

    f32x4 Oacc[8];
#pragma unroll
    for (int i = 0; i < 8; ++i) Oacc[i] = (f32x4){0.f, 0.f, 0.f, 0.f};
    float m_run = -1e30f, l_run = 0.f;

    // preload tile 0
    {
      const float* kp = K + base + (size_t)krow * DH + kcolf;
#pragma unroll
      for (int q = 0; q < 8; ++q) ka[q] = *(const f32x4*)(kp + q * 4);
#pragma unroll
      for (int kk = 0; kk < 2; ++kk) {
        const float* vp = V + base + (size_t)(vkb + kk * 32) * DH + vd;
#pragma unroll
        for (int i = 0; i < 4; ++i) va[kk * 4 + i] = *(const f32x4*)(vp + i * DH);
      }
    }

#pragma unroll 1
    for (int kt = 0; kt < nkt; ++kt) {
      const int k0 = kt * 64;

      // ---- write staged tile to LDS ----
#pragma unroll
      for (int q2 = 0; q2 < 4; ++q2) {
        f32x4 a = ka[2 * q2], b = ka[2 * q2 + 1];
        union { h16x8 v; unsigned u[4]; } t;
        t.u[0] = pk2(a[0], a[1]); t.u[1] = pk2(a[2], a[3]);
        t.u[2] = pk2(b[0], b[1]); t.u[3] = pk2(b[2], b[3]);
        *(h16x8*)&Ks[krow * KPAD + kcolf + q2 * 8] = t.v;
      }
#pragma unroll
      for (int kk = 0; kk < 2; ++kk) {
        const int c = (vkb + kk * 32) >> 2;
#pragma unroll
        for (int j = 0; j < 4; ++j) {
          const int row = vd + j;
          const int mm = (row ^ (row >> 4)) & 14;
          union { h16x4 v; unsigned u[2]; } t;
          t.u[0] = pk2(va[kk * 4 + 0][j], va[kk * 4 + 1][j]);
          t.u[1] = pk2(va[kk * 4 + 2][j], va[kk * 4 + 3][j]);
          *(h16x4*)&Vt[row * VPAD + ((c ^ mm) << 2)] = t.v;
        }
      }
      __syncthreads();

      // ---- prefetch next tile (in-flight across compute) ----
      if (kt + 1 < nkt) {
        const int kn = k0 + 64;
        const float* kp = K + base + (size_t)(kn + krow) * DH + kcolf;
#pragma unroll
        for (int q = 0; q < 8; ++q) ka[q] = *(const f32x4*)(kp + q * 4);
#pragma unroll
        for (int kk = 0; kk < 2; ++kk) {
          const float* vp = V + base + (size_t)(kn + vkb + kk * 32) * DH + vd;
#pragma unroll
          for (int i = 0; i < 4; ++i) va[kk * 4 + i] = *(const f32x4*)(vp + i * DH);
        }
      }

      // ---- S^T = K * Qs^T (row=key, col=query) ----
      f32x4 st[4];
#pragma unroll
      for (int t = 0; t < 4; ++t) st[t] = (f32x4){0.f, 0.f, 0.f, 0.f};
#pragma unroll
      for (int t = 0; t < 4; ++t)
#pragma unroll
        for (int f = 0; f < 4; ++f) {
          h16x8 kf = *(const h16x8*)&Ks[(t * 16 + l16) * KPAD + f * 32 + quad * 8];
          st[t] = __builtin_amdgcn_mfma_f32_16x16x32_f16(kf, qf[f], st[t], 0, 0, 0);
        }

      // ---- causal mask (diagonal tile only; block-uniform branch) ----
      if (k0 + 63 > q0 + w * 16) {
#pragma unroll
        for (int t = 0; t < 4; ++t)
#pragma unroll
          for (int r = 0; r < 4; ++r)
            if (k0 + t * 16 + quad * 4 + r > qrow) st[t][r] = -1e30f;
      }

      // ---- online softmax in log2 domain (per query = per l16 column) ----
      float mt = st[0][0];
#pragma unroll
      for (int t = 0; t < 4; ++t)
#pragma unroll
        for (int r = 0; r < 4; ++r) mt = fmaxf(mt, st[t][r]);
      mt = fmaxf(mt, __shfl_xor(mt, 16));
      mt = fmaxf(mt, __shfl_xor(mt, 32));
      const float m_new = fmaxf(m_run, mt);
      float p[16], rs = 0.f;
#pragma unroll
      for (int t = 0; t < 4; ++t)
#pragma unroll
        for (int r = 0; r < 4; ++r) { p[t * 4 + r] = EXP2(st[t][r] - m_new); rs += p[t * 4 + r]; }
      rs += __shfl_xor(rs, 16);
      rs += __shfl_xor(rs, 32);
      const float alpha = EXP2(m_run - m_new);
      l_run = l_run * alpha + rs;
      m_run = m_new;

      float aO[4];
#pragma unroll
      for (int r = 0; r < 4; ++r) aO[r] = __shfl(alpha, quad * 4 + r);
#pragma unroll
      for (int dt = 0; dt < 8; ++dt)
#pragma unroll
        for (int r = 0; r < 4; ++r) Oacc[dt][r] *= aO[r];

      // ---- pack P, C-layout -> A-layout via shuffles, then O += P*V ----
      int pd[8];
#pragma unroll
      for (int t = 0; t < 4; ++t) {
        pd[t * 2]     = (int)pk2(p[t * 4 + 0], p[t * 4 + 1]);
        pd[t * 2 + 1] = (int)pk2(p[t * 4 + 2], p[t * 4 + 3]);
      }
#pragma unroll
      for (int h = 0; h < 2; ++h) {
        union { h16x8 v; int u[4]; } pa;
#pragma unroll
        for (int hp = 0; hp < 4; ++hp) {
          const int src = (2 * (quad & 1) + (hp >> 1)) * 16 + l16;
          const int va_ = __shfl(pd[4 * h + (hp & 1)], src);
          const int vb_ = __shfl(pd[4 * h + 2 + (hp & 1)], src);
          pa.u[hp] = (quad >= 2) ? vb_ : va_;
        }
#pragma unroll
        for (int dt = 0; dt < 8; ++dt) {
          const int off0 = vrow[dt] + (voff[dt] ^ (h << 5));
          h16x8 vf = *(const h16x8*)&Vt[off0];
          Oacc[dt] = __builtin_amdgcn_mfma_f32_16x16x32_f16(pa.v, vf, Oacc[dt], 0, 0, 0);
        }
      }
      __syncthreads();
    }

    // ---- epilogue: normalize, store ----
    float lO[4];
#pragma unroll
    for (int r = 0; r < 4; ++r) lO[r] = 1.0f / __shfl(l_run, quad * 4 + r);
#pragma unroll
    for (int dt = 0; dt < 8; ++dt)
#pragma unroll
      for (int r = 0; r < 4; ++r) {
        const size_t row = q0 + w * 16 + quad * 4 + r;
        O[base + row * DH + dt * 16 + l16] = Oacc[dt][r] * lO[r];
      }
  }
}

extern "C" void kernel_launch(void* const* d_in, const int* in_sizes, int n_in,
                              void* d_out, int out_size, void* d_ws, size_t ws_size,
                              hipStream_t stream) {
  const float* Q  = (const float*)d_in[0];
  const float* K  = (const float*)d_in[1];
  const float* V  = (const float*)d_in[2];
  const float* sc = (const float*)d_in[3];
  float* O = (float*)d_out;
  dim3 grid(NQT / 2, NBH);
  attn_fwd<<<grid, dim3(256), 0, stream>>>(Q, K, V, sc, O);
}

// Round 6
// 246.723 us; speedup vs baseline: 1.2864x; 1.0726x over previous
//
#include <hip/hip_runtime.h>
#include <hip/hip_bf16.h>

#define S_LEN 2048
#define DH    128
#define NBH   32
#define KPAD  136         // Ks row pitch in halves (272B)
#define VPAD  72          // Vt row pitch in halves (144B)

typedef __attribute__((ext_vector_type(4))) float    f32x4;
typedef __attribute__((ext_vector_type(8))) _Float16 h16x8;
typedef __attribute__((ext_vector_type(4))) _Float16 h16x4;
typedef __attribute__((ext_vector_type(2))) __fp16   fp16x2;

#if __has_builtin(__builtin_amdgcn_exp2f)
#define EXP2(x) __builtin_amdgcn_exp2f(x)
#else
#define EXP2(x) exp2f(x)
#endif

static __device__ __forceinline__ unsigned pk2(float lo, float hi) {
  union { fp16x2 h; unsigned u; } u;
  u.h = __builtin_amdgcn_cvt_pkrtz(lo, hi);
  return u.u;
}

// Block = two 64-row q-strips (jq and 31-jq) of one (b,h), carried through ONE
// k-sweep (strip-low active only while kt <= jq). 4 waves x 16 rows per strip.
// XCD swizzle keeps all 16 blocks of a (b,h) on one XCD so K/V stay L2-resident.
__global__ __launch_bounds__(256, 2)
void attn_fwd(const float* __restrict__ Q, const float* __restrict__ K,
              const float* __restrict__ V, const float* __restrict__ scale,
              float* __restrict__ O) {
  __shared__ short Ks[64 * KPAD];   // K tile row-major f16
  __shared__ short Vt[128 * VPAD];  // V tile transposed, 4-half-block XOR swizzled

  const int tid  = threadIdx.x;
  const int w    = tid >> 6;
  const int lane = tid & 63;
  const int quad = lane >> 4;
  const int l16  = lane & 15;

  // flat = (bh&7) | (jq<<3) | ((bh>>3)<<7): flat%8 == bh%8 -> one XCD per (b,h)
  const int flat = (int)blockIdx.x;
  const int jq   = (flat >> 3) & 15;
  const int bh   = (flat & 7) | ((flat >> 7) << 3);

  const size_t base = (size_t)bh * (S_LEN * DH);
  const float sc = scale[0] * 1.44269504088896340736f;  // fold log2(e)

  // staging indices
  const int krow = tid >> 2, kcolf = (tid & 3) * 32;    // K: 4 threads/row
  const int vd = (tid & 31) * 4, vkb = (tid >> 5) * 4;  // V: 4k x 4d transpose

  // Vt read addressing: row base and within-row swizzled offset kept separate.
  int vrow[8], voff[8];
#pragma unroll
  for (int dt = 0; dt < 8; ++dt) {
    const int row = dt * 16 + l16;
    const int mm = (row ^ (row >> 4)) & 14;
    vrow[dt] = row * VPAD;
    voff[dt] = ((quad * 2) ^ mm) << 2;
  }

  const int q0A = jq * 64;           // low strip (short causal range)
  const int q0B = (31 - jq) * 64;    // high strip
  const int nkt = 32 - jq;           // k-tiles for strip B (superset of A's)
  const int qrowA = q0A + w * 16 + l16;
  const int qrowB = q0B + w * 16 + l16;

  // Q fragments (B-operand), pre-scaled by scale*log2e
  h16x8 qfA[4], qfB[4];
  {
    const float* qpA = Q + base + (size_t)qrowA * DH + quad * 8;
    const float* qpB = Q + base + (size_t)qrowB * DH + quad * 8;
#pragma unroll
    for (int f = 0; f < 4; ++f) {
      f32x4 a = *(const f32x4*)(qpA + f * 32);
      f32x4 b = *(const f32x4*)(qpA + f * 32 + 4);
      union { h16x8 v; unsigned u[4]; } t;
      t.u[0] = pk2(a[0] * sc, a[1] * sc);
      t.u[1] = pk2(a[2] * sc, a[3] * sc);
      t.u[2] = pk2(b[0] * sc, b[1] * sc);
      t.u[3] = pk2(b[2] * sc, b[3] * sc);
      qfA[f] = t.v;
      a = *(const f32x4*)(qpB + f * 32);
      b = *(const f32x4*)(qpB + f * 32 + 4);
      t.u[0] = pk2(a[0] * sc, a[1] * sc);
      t.u[1] = pk2(a[2] * sc, a[3] * sc);
      t.u[2] = pk2(b[0] * sc, b[1] * sc);
      t.u[3] = pk2(b[2] * sc, b[3] * sc);
      qfB[f] = t.v;
    }
  }

  f32x4 OA[8], OB[8];
#pragma unroll
  for (int i = 0; i < 8; ++i) { OA[i] = (f32x4){0.f,0.f,0.f,0.f}; OB[i] = (f32x4){0.f,0.f,0.f,0.f}; }
  float mA = -1e30f, lA = 0.f, mB = -1e30f, lB = 0.f;

  // online softmax + O-rescale + P-pack for one strip (per query = l16 column)
  auto softmax_pack = [&](f32x4* st, float& m_run, float& l_run, f32x4* Oacc, int* pd) {
    float mt = st[0][0];
#pragma unroll
    for (int t = 0; t < 4; ++t)
#pragma unroll
      for (int r = 0; r < 4; ++r) mt = fmaxf(mt, st[t][r]);
    mt = fmaxf(mt, __shfl_xor(mt, 16));
    mt = fmaxf(mt, __shfl_xor(mt, 32));
    const float m_new = fmaxf(m_run, mt);
    float p[16], rs = 0.f;
#pragma unroll
    for (int t = 0; t < 4; ++t)
#pragma unroll
      for (int r = 0; r < 4; ++r) { p[t*4+r] = EXP2(st[t][r] - m_new); rs += p[t*4+r]; }
    rs += __shfl_xor(rs, 16);
    rs += __shfl_xor(rs, 32);
    const float alpha = EXP2(m_run - m_new);
    l_run = l_run * alpha + rs;
    m_run = m_new;
    float aO[4];
#pragma unroll
    for (int r = 0; r < 4; ++r) aO[r] = __shfl(alpha, quad * 4 + r);
#pragma unroll
    for (int dt = 0; dt < 8; ++dt)
#pragma unroll
      for (int r = 0; r < 4; ++r) Oacc[dt][r] *= aO[r];
#pragma unroll
    for (int t = 0; t < 4; ++t) {
      pd[t*2]   = (int)pk2(p[t*4+0], p[t*4+1]);
      pd[t*2+1] = (int)pk2(p[t*4+2], p[t*4+3]);
    }
  };

  f32x4 ka[8], va[8];  // register prefetch of next K/V tile
  {
    const float* kp = K + base + (size_t)krow * DH + kcolf;
#pragma unroll
    for (int q = 0; q < 8; ++q) ka[q] = *(const f32x4*)(kp + q * 4);
#pragma unroll
    for (int kk = 0; kk < 2; ++kk) {
      const float* vp = V + base + (size_t)(vkb + kk * 32) * DH + vd;
#pragma unroll
      for (int i = 0; i < 4; ++i) va[kk*4+i] = *(const f32x4*)(vp + i * DH);
    }
  }

#pragma unroll 1
  for (int kt = 0; kt < nkt; ++kt) {
    const int k0 = kt * 64;

    // ---- write staged tile to LDS ----
#pragma unroll
    for (int q2 = 0; q2 < 4; ++q2) {
      f32x4 a = ka[2*q2], b = ka[2*q2+1];
      union { h16x8 v; unsigned u[4]; } t;
      t.u[0] = pk2(a[0], a[1]); t.u[1] = pk2(a[2], a[3]);
      t.u[2] = pk2(b[0], b[1]); t.u[3] = pk2(b[2], b[3]);
      *(h16x8*)&Ks[krow * KPAD + kcolf + q2 * 8] = t.v;
    }
#pragma unroll
    for (int kk = 0; kk < 2; ++kk) {
      const int c = (vkb + kk * 32) >> 2;
#pragma unroll
      for (int j = 0; j < 4; ++j) {
        const int row = vd + j;
        const int mm = (row ^ (row >> 4)) & 14;
        union { h16x4 v; unsigned u[2]; } t;
        t.u[0] = pk2(va[kk*4+0][j], va[kk*4+1][j]);
        t.u[1] = pk2(va[kk*4+2][j], va[kk*4+3][j]);
        *(h16x4*)&Vt[row * VPAD + ((c ^ mm) << 2)] = t.v;
      }
    }
    __syncthreads();

    // ---- prefetch next tile ----
    if (kt + 1 < nkt) {
      const int kn = k0 + 64;
      const float* kp = K + base + (size_t)(kn + krow) * DH + kcolf;
#pragma unroll
      for (int q = 0; q < 8; ++q) ka[q] = *(const f32x4*)(kp + q * 4);
#pragma unroll
      for (int kk = 0; kk < 2; ++kk) {
        const float* vp = V + base + (size_t)(kn + vkb + kk * 32) * DH + vd;
#pragma unroll
        for (int i = 0; i < 4; ++i) va[kk*4+i] = *(const f32x4*)(vp + i * DH);
      }
    }

    const bool actA = (kt <= jq);  // block-uniform

    // ---- S^T = K * Qs^T, K-fragments shared between strips ----
    f32x4 stA[4], stB[4];
#pragma unroll
    for (int t = 0; t < 4; ++t) { stA[t] = (f32x4){0.f,0.f,0.f,0.f}; stB[t] = (f32x4){0.f,0.f,0.f,0.f}; }
#pragma unroll
    for (int t = 0; t < 4; ++t)
#pragma unroll
      for (int f = 0; f < 4; ++f) {
        h16x8 kf = *(const h16x8*)&Ks[(t * 16 + l16) * KPAD + f * 32 + quad * 8];
        stB[t] = __builtin_amdgcn_mfma_f32_16x16x32_f16(kf, qfB[f], stB[t], 0, 0, 0);
        if (actA) stA[t] = __builtin_amdgcn_mfma_f32_16x16x32_f16(kf, qfA[f], stA[t], 0, 0, 0);
      }

    // ---- causal masks (diagonal tiles only) ----
    if (kt == nkt - 1) {  // k0 == q0B
#pragma unroll
      for (int t = 0; t < 4; ++t)
#pragma unroll
        for (int r = 0; r < 4; ++r)
          if (k0 + t * 16 + quad * 4 + r > qrowB) stB[t][r] = -1e30f;
    }
    int pdA[8], pdB[8];
    softmax_pack(stB, mB, lB, OB, pdB);
    if (actA) {
      if (kt == jq) {   // k0 == q0A
#pragma unroll
        for (int t = 0; t < 4; ++t)
#pragma unroll
          for (int r = 0; r < 4; ++r)
            if (k0 + t * 16 + quad * 4 + r > qrowA) stA[t][r] = -1e30f;
      }
      softmax_pack(stA, mA, lA, OA, pdA);
    }

    // ---- P transform (C->A layout) + O += P*V, V-fragments shared ----
#pragma unroll
    for (int h = 0; h < 2; ++h) {
      union { h16x8 v; int u[4]; } paA, paB;
#pragma unroll
      for (int hp = 0; hp < 4; ++hp) {
        const int src = (2 * (quad & 1) + (hp >> 1)) * 16 + l16;
        int va_ = __shfl(pdB[4*h + (hp & 1)], src);
        int vb_ = __shfl(pdB[4*h + 2 + (hp & 1)], src);
        paB.u[hp] = (quad >= 2) ? vb_ : va_;
        if (actA) {
          va_ = __shfl(pdA[4*h + (hp & 1)], src);
          vb_ = __shfl(pdA[4*h + 2 + (hp & 1)], src);
          paA.u[hp] = (quad >= 2) ? vb_ : va_;
        }
      }
#pragma unroll
      for (int dt = 0; dt < 8; ++dt) {
        const int off0 = vrow[dt] + (voff[dt] ^ (h << 5));
        h16x8 vf = *(const h16x8*)&Vt[off0];
        OB[dt] = __builtin_amdgcn_mfma_f32_16x16x32_f16(paB.v, vf, OB[dt], 0, 0, 0);
        if (actA) OA[dt] = __builtin_amdgcn_mfma_f32_16x16x32_f16(paA.v, vf, OA[dt], 0, 0, 0);
      }
    }
    __syncthreads();
  }

  // ---- epilogue: normalize and store both strips ----
  auto store_o = [&](f32x4* Oacc, float l_run, int q0) {
    float lO[4];
#pragma unroll
    for (int r = 0; r < 4; ++r) lO[r] = 1.0f / __shfl(l_run, quad * 4 + r);
#pragma unroll
    for (int dt = 0; dt < 8; ++dt)
#pragma unroll
      for (int r = 0; r < 4; ++r) {
        const size_t row = q0 + w * 16 + quad * 4 + r;
        O[base + row * DH + dt * 16 + l16] = Oacc[dt][r] * lO[r];
      }
  };
  store_o(OB, lB, q0B);
  store_o(OA, lA, q0A);
}

extern "C" void kernel_launch(void* const* d_in, const int* in_sizes, int n_in,
                              void* d_out, int out_size, void* d_ws, size_t ws_size,
                              hipStream_t stream) {
  const float* Q  = (const float*)d_in[0];
  const float* K  = (const float*)d_in[1];
  const float* V  = (const float*)d_in[2];
  const float* sc = (const float*)d_in[3];
  float* O = (float*)d_out;
  attn_fwd<<<dim3(512), dim3(256), 0, stream>>>(Q, K, V, sc, O);
}

// Round 7
// 242.278 us; speedup vs baseline: 1.3100x; 1.0183x over previous
//
#include <hip/hip_runtime.h>
#include <hip/hip_bf16.h>

#define S_LEN 2048
#define DH    128
#define NBH   32
#define KPAD  136         // Ks row pitch in halves (272B)
#define VPAD  72          // Vt row pitch in halves (144B)

typedef __attribute__((ext_vector_type(4))) float    f32x4;
typedef __attribute__((ext_vector_type(8))) _Float16 h16x8;
typedef __attribute__((ext_vector_type(4))) _Float16 h16x4;
typedef __attribute__((ext_vector_type(2))) __fp16   fp16x2;

#if __has_builtin(__builtin_amdgcn_exp2f)
#define EXP2(x) __builtin_amdgcn_exp2f(x)
#else
#define EXP2(x) exp2f(x)
#endif

static __device__ __forceinline__ unsigned pk2(float lo, float hi) {
  union { fp16x2 h; unsigned u; } u;
  u.h = __builtin_amdgcn_cvt_pkrtz(lo, hi);
  return u.u;
}

// Block = two 64-row q-strips (jq and 31-jq) of one (b,h), ONE k-sweep.
// XCD swizzle: flat%8 == bh%8 -> all 16 blocks of a (b,h) on one XCD (K/V L2-resident).
// Complementary pairing: CU slots m and m+32 get jq and 15-jq -> 49 iters per CU.
// Double-buffered LDS: ONE barrier per k-iteration.
__global__ __launch_bounds__(256, 2)
void attn_fwd(const float* __restrict__ Q, const float* __restrict__ K,
              const float* __restrict__ V, const float* __restrict__ scale,
              float* __restrict__ O) {
  __shared__ short Ks[2][64 * KPAD];
  __shared__ short Vt[2][128 * VPAD];

  const int tid  = threadIdx.x;
  const int w    = tid >> 6;
  const int lane = tid & 63;
  const int quad = lane >> 4;
  const int l16  = lane & 15;

  const int flat = (int)blockIdx.x;
  const int m_   = flat >> 3;
  const int jqi  = m_ & 15;
  const int bhh  = m_ >> 4;                       // 0..3
  const int jq   = (bhh & 2) ? (15 - jqi) : jqi;  // complement on second CU slot
  const int bh   = (flat & 7) | (bhh << 3);

  const size_t base = (size_t)bh * (S_LEN * DH);
  const float sc = scale[0] * 1.44269504088896340736f;  // fold log2(e)

  const int krow = tid >> 2, kcolf = (tid & 3) * 32;    // K staging: 4 thr/row
  const int vd = (tid & 31) * 4, vkb = (tid >> 5) * 4;  // V staging: 4k x 4d transpose

  int vrow[8], voff[8];
#pragma unroll
  for (int dt = 0; dt < 8; ++dt) {
    const int row = dt * 16 + l16;
    const int mm = (row ^ (row >> 4)) & 14;
    vrow[dt] = row * VPAD;
    voff[dt] = ((quad * 2) ^ mm) << 2;
  }

  const int q0A = jq * 64;
  const int q0B = (31 - jq) * 64;
  const int nkt = 32 - jq;
  const int qrowA = q0A + w * 16 + l16;
  const int qrowB = q0B + w * 16 + l16;

  h16x8 qfA[4], qfB[4];
  {
    const float* qpA = Q + base + (size_t)qrowA * DH + quad * 8;
    const float* qpB = Q + base + (size_t)qrowB * DH + quad * 8;
#pragma unroll
    for (int f = 0; f < 4; ++f) {
      f32x4 a = *(const f32x4*)(qpA + f * 32);
      f32x4 b = *(const f32x4*)(qpA + f * 32 + 4);
      union { h16x8 v; unsigned u[4]; } t;
      t.u[0] = pk2(a[0] * sc, a[1] * sc);
      t.u[1] = pk2(a[2] * sc, a[3] * sc);
      t.u[2] = pk2(b[0] * sc, b[1] * sc);
      t.u[3] = pk2(b[2] * sc, b[3] * sc);
      qfA[f] = t.v;
      a = *(const f32x4*)(qpB + f * 32);
      b = *(const f32x4*)(qpB + f * 32 + 4);
      t.u[0] = pk2(a[0] * sc, a[1] * sc);
      t.u[1] = pk2(a[2] * sc, a[3] * sc);
      t.u[2] = pk2(b[0] * sc, b[1] * sc);
      t.u[3] = pk2(b[2] * sc, b[3] * sc);
      qfB[f] = t.v;
    }
  }

  f32x4 OA[8], OB[8];
#pragma unroll
  for (int i = 0; i < 8; ++i) { OA[i] = (f32x4){0.f,0.f,0.f,0.f}; OB[i] = (f32x4){0.f,0.f,0.f,0.f}; }
  float mA = -1e30f, lA = 0.f, mB = -1e30f, lB = 0.f;

  auto softmax_pack = [&](f32x4* st, float& m_run, float& l_run, f32x4* Oacc, int* pd) {
    float mt = st[0][0];
#pragma unroll
    for (int t = 0; t < 4; ++t)
#pragma unroll
      for (int r = 0; r < 4; ++r) mt = fmaxf(mt, st[t][r]);
    mt = fmaxf(mt, __shfl_xor(mt, 16));
    mt = fmaxf(mt, __shfl_xor(mt, 32));
    const float m_new = fmaxf(m_run, mt);
    float p[16], rs = 0.f;
#pragma unroll
    for (int t = 0; t < 4; ++t)
#pragma unroll
      for (int r = 0; r < 4; ++r) { p[t*4+r] = EXP2(st[t][r] - m_new); rs += p[t*4+r]; }
    rs += __shfl_xor(rs, 16);
    rs += __shfl_xor(rs, 32);
    const float alpha = EXP2(m_run - m_new);
    l_run = l_run * alpha + rs;
    m_run = m_new;
    float aO[4];
#pragma unroll
    for (int r = 0; r < 4; ++r) aO[r] = __shfl(alpha, quad * 4 + r);
#pragma unroll
    for (int dt = 0; dt < 8; ++dt)
#pragma unroll
      for (int r = 0; r < 4; ++r) Oacc[dt][r] *= aO[r];
#pragma unroll
    for (int t = 0; t < 4; ++t) {
      pd[t*2]   = (int)pk2(p[t*4+0], p[t*4+1]);
      pd[t*2+1] = (int)pk2(p[t*4+2], p[t*4+3]);
    }
  };

  f32x4 ka[8], va[8];
  auto load_tile = [&](int k0) {
    const float* kp = K + base + (size_t)(k0 + krow) * DH + kcolf;
#pragma unroll
    for (int q = 0; q < 8; ++q) ka[q] = *(const f32x4*)(kp + q * 4);
#pragma unroll
    for (int kk = 0; kk < 2; ++kk) {
      const float* vp = V + base + (size_t)(k0 + vkb + kk * 32) * DH + vd;
#pragma unroll
      for (int i = 0; i < 4; ++i) va[kk*4+i] = *(const f32x4*)(vp + i * DH);
    }
  };
  auto write_tile = [&](int buf) {
    short* ksw = Ks[buf];
    short* vtw = Vt[buf];
#pragma unroll
    for (int q2 = 0; q2 < 4; ++q2) {
      f32x4 a = ka[2*q2], b = ka[2*q2+1];
      union { h16x8 v; unsigned u[4]; } t;
      t.u[0] = pk2(a[0], a[1]); t.u[1] = pk2(a[2], a[3]);
      t.u[2] = pk2(b[0], b[1]); t.u[3] = pk2(b[2], b[3]);
      *(h16x8*)&ksw[krow * KPAD + kcolf + q2 * 8] = t.v;
    }
#pragma unroll
    for (int kk = 0; kk < 2; ++kk) {
      const int c = (vkb + kk * 32) >> 2;
#pragma unroll
      for (int j = 0; j < 4; ++j) {
        const int row = vd + j;
        const int mm = (row ^ (row >> 4)) & 14;
        union { h16x4 v; unsigned u[2]; } t;
        t.u[0] = pk2(va[kk*4+0][j], va[kk*4+1][j]);
        t.u[1] = pk2(va[kk*4+2][j], va[kk*4+3][j]);
        *(h16x4*)&vtw[row * VPAD + ((c ^ mm) << 2)] = t.v;
      }
    }
  };

  // prologue: tile 0 -> buf 0
  load_tile(0);
  write_tile(0);
  __syncthreads();

#pragma unroll 1
  for (int kt = 0; kt < nkt; ++kt) {
    const int k0 = kt * 64;
    const int buf = kt & 1;
    const bool more = (kt + 1 < nkt);

    if (more) load_tile(k0 + 64);   // in flight across compute

    const bool actA = (kt <= jq);
    const bool diagA = (kt == jq);
    const bool diagB = (kt == nkt - 1);
    const short* ksb = Ks[buf];
    const short* vtb = Vt[buf];

    // ---- S^T = K * Qs^T (K-fragments shared between strips) ----
    f32x4 stA[4], stB[4];
#pragma unroll
    for (int t = 0; t < 4; ++t) { stA[t] = (f32x4){0.f,0.f,0.f,0.f}; stB[t] = (f32x4){0.f,0.f,0.f,0.f}; }
#pragma unroll
    for (int t = 0; t < 4; ++t) {
      const bool needB = !diagB || (t <= w);          // skip fully-masked diag tiles
      const bool needA = actA && (!diagA || (t <= w));
      if (needB || needA) {
#pragma unroll
        for (int f = 0; f < 4; ++f) {
          h16x8 kf = *(const h16x8*)&ksb[(t * 16 + l16) * KPAD + f * 32 + quad * 8];
          if (needB) stB[t] = __builtin_amdgcn_mfma_f32_16x16x32_f16(kf, qfB[f], stB[t], 0, 0, 0);
          if (needA) stA[t] = __builtin_amdgcn_mfma_f32_16x16x32_f16(kf, qfA[f], stA[t], 0, 0, 0);
        }
      }
    }

    // ---- causal masks (diagonal tiles only) ----
    if (diagB) {
#pragma unroll
      for (int t = 0; t < 4; ++t)
#pragma unroll
        for (int r = 0; r < 4; ++r)
          if (k0 + t * 16 + quad * 4 + r > qrowB) stB[t][r] = -1e30f;
    }
    int pdA[8], pdB[8];
    softmax_pack(stB, mB, lB, OB, pdB);
    if (actA) {
      if (diagA) {
#pragma unroll
        for (int t = 0; t < 4; ++t)
#pragma unroll
          for (int r = 0; r < 4; ++r)
            if (k0 + t * 16 + quad * 4 + r > qrowA) stA[t][r] = -1e30f;
      }
      softmax_pack(stA, mA, lA, OA, pdA);
    }

    // ---- P transform (C->A layout) + O += P*V (V-fragments shared) ----
#pragma unroll
    for (int h = 0; h < 2; ++h) {
      union { h16x8 v; int u[4]; } paA, paB;
#pragma unroll
      for (int hp = 0; hp < 4; ++hp) {
        const int src = (2 * (quad & 1) + (hp >> 1)) * 16 + l16;
        int va_ = __shfl(pdB[4*h + (hp & 1)], src);
        int vb_ = __shfl(pdB[4*h + 2 + (hp & 1)], src);
        paB.u[hp] = (quad >= 2) ? vb_ : va_;
        if (actA) {
          va_ = __shfl(pdA[4*h + (hp & 1)], src);
          vb_ = __shfl(pdA[4*h + 2 + (hp & 1)], src);
          paA.u[hp] = (quad >= 2) ? vb_ : va_;
        }
      }
#pragma unroll
      for (int dt = 0; dt < 8; ++dt) {
        const int off0 = vrow[dt] + (voff[dt] ^ (h << 5));
        h16x8 vf = *(const h16x8*)&vtb[off0];
        OB[dt] = __builtin_amdgcn_mfma_f32_16x16x32_f16(paB.v, vf, OB[dt], 0, 0, 0);
        if (actA) OA[dt] = __builtin_amdgcn_mfma_f32_16x16x32_f16(paA.v, vf, OA[dt], 0, 0, 0);
      }
    }

    if (more) write_tile(buf ^ 1);  // next tile into other buffer
    __syncthreads();                // single barrier per iteration
  }

  // ---- epilogue ----
  auto store_o = [&](f32x4* Oacc, float l_run, int q0) {
    float lO[4];
#pragma unroll
    for (int r = 0; r < 4; ++r) lO[r] = 1.0f / __shfl(l_run, quad * 4 + r);
#pragma unroll
    for (int dt = 0; dt < 8; ++dt)
#pragma unroll
      for (int r = 0; r < 4; ++r) {
        const size_t row = q0 + w * 16 + quad * 4 + r;
        O[base + row * DH + dt * 16 + l16] = Oacc[dt][r] * lO[r];
      }
  };
  store_o(OB, lB, q0B);
  store_o(OA, lA, q0A);
}

extern "C" void kernel_launch(void* const* d_in, const int* in_sizes, int n_in,
                              void* d_out, int out_size, void* d_ws, size_t ws_size,
                              hipStream_t stream) {
  const float* Q  = (const float*)d_in[0];
  const float* K  = (const float*)d_in[1];
  const float* V  = (const float*)d_in[2];
  const float* sc = (const float*)d_in[3];
  float* O = (float*)d_out;
  attn_fwd<<<dim3(512), dim3(256), 0, stream>>>(Q, K, V, sc, O);
}